// Round 1
// baseline (274.031 us; speedup 1.0000x reference)
//
#include <hip/hip_runtime.h>

#define NQ 10
#define NSAMP 16384
#define BN_EPS 1e-5f

__device__ __forceinline__ float shflx(float v, int m) {
  return __shfl_xor(v, m, 64);
}

// General SU(2) gate  [[w, -conj(v)], [v, conj(w)]]  on register-bit RBIT (0..3)
template<int RBIT>
__device__ __forceinline__ void gate_reg(float* sr, float* si,
                                         float wr, float wi, float vr, float vi) {
  constexpr int m = 1 << RBIT;
  #pragma unroll
  for (int r = 0; r < 16; ++r) {
    if (!(r & m)) {
      const int r1 = r | m;
      float a0r = sr[r], a0i = si[r], a1r = sr[r1], a1i = si[r1];
      sr[r]  = wr*a0r - wi*a0i - vr*a1r - vi*a1i;
      si[r]  = wr*a0i + wi*a0r - vr*a1i + vi*a1r;
      sr[r1] = vr*a0r - vi*a0i + wr*a1r + wi*a1i;
      si[r1] = vr*a0i + vi*a0r + wr*a1i - wi*a1r;
    }
  }
}

// Same gate on a lane bit (xor mask lm on lane id)
__device__ __forceinline__ void gate_lane(float* sr, float* si, int lm, int lane,
                                          float wr, float wi, float vr, float vi) {
  const bool hi = (lane & lm) != 0;
  const float scr = wr;
  const float sci = hi ? -wi : wi;
  const float pcr = hi ? vr : -vr;
  const float pci = vi;
  #pragma unroll
  for (int r = 0; r < 16; ++r) {
    float br = shflx(sr[r], lm);
    float bi = shflx(si[r], lm);
    float ar = sr[r], ai = si[r];
    sr[r] = scr*ar - sci*ai + pcr*br - pci*bi;
    si[r] = scr*ai + sci*ar + pcr*bi + pci*br;
  }
}

template<int BIT>
__device__ __forceinline__ void apply_gate(float* sr, float* si, int lane,
                                           float wr, float wi, float vr, float vi) {
  if constexpr (BIT <= 3) gate_reg<BIT>(sr, si, wr, wi, vr, vi);
  else                    gate_lane(sr, si, 1 << (BIT - 4), lane, wr, wi, vr, vi);
}

// RY encoding gate: w=(c,0), v=(s,0)
template<int Q>
__device__ __forceinline__ void enc_gate(const float* xrow, float* sr, float* si, int lane) {
  float t = xrow[Q] * 0.5f;
  float s, c;
  __sincosf(t, &s, &c);
  apply_gate<9 - Q>(sr, si, lane, c, 0.f, s, 0.f);
}

// Fused RZ*RX*RY gate with precomputed coefficients
template<int Q>
__device__ __forceinline__ void rot_gate(const float* coef, int l, float* sr, float* si, int lane) {
  const float* cg = coef + (l * 10 + Q) * 4;
  apply_gate<9 - Q>(sr, si, lane, cg[0], cg[1], cg[2], cg[3]);
}

// CNOT, both bits in lane id: control mask clm, target mask tlm
__device__ __forceinline__ void cnot_ll(float* sr, float* si, int lane, int clm, int tlm) {
  const bool ctrl = (lane & clm) != 0;
  #pragma unroll
  for (int r = 0; r < 16; ++r) {
    float pr = shflx(sr[r], tlm);
    float pi = shflx(si[r], tlm);
    sr[r] = ctrl ? pr : sr[r];
    si[r] = ctrl ? pi : si[r];
  }
}

// CNOT: control = lane bit 0, target = reg bit 3
__device__ __forceinline__ void cnot_l0_r3(float* sr, float* si, int lane) {
  const bool ctrl = (lane & 1) != 0;
  #pragma unroll
  for (int r = 0; r < 8; ++r) {
    float t0r = sr[r], t1r = sr[r | 8];
    sr[r]     = ctrl ? t1r : t0r;
    sr[r | 8] = ctrl ? t0r : t1r;
    float t0i = si[r], t1i = si[r | 8];
    si[r]     = ctrl ? t1i : t0i;
    si[r | 8] = ctrl ? t0i : t1i;
  }
}

// CNOT: both bits in registers -> unconditional compile-time register swap (free)
template<int CB, int TB>
__device__ __forceinline__ void cnot_rr(float* sr, float* si) {
  constexpr int cm = 1 << CB, tm = 1 << TB;
  #pragma unroll
  for (int r = 0; r < 16; ++r) {
    if ((r & cm) && !(r & tm)) {
      const int r1 = r | tm;
      float t;
      t = sr[r]; sr[r] = sr[r1]; sr[r1] = t;
      t = si[r]; si[r] = si[r1]; si[r1] = t;
    }
  }
}

// K0: 30 fused SU(2) matrices from params (batch-uniform)
__global__ void coef_kernel(const float* __restrict__ params, float* __restrict__ coef) {
  int g = threadIdx.x;
  if (g < 30) {
    float t0 = params[g * 3 + 0] * 0.5f;
    float t1 = params[g * 3 + 1] * 0.5f;
    float t2 = params[g * 3 + 2] * 0.5f;
    float sa, ca, s2, c2, s3, c3;
    __sincosf(t0, &sa, &ca);
    __sincosf(t1, &s2, &c2);
    __sincosf(t2, &s3, &c3);
    float A = c3 * c2, Bv = s3 * s2, C = s3 * c2, D = c3 * s2;
    coef[g * 4 + 0] = A * ca + Bv * sa;      // wr
    coef[g * 4 + 1] = Bv * ca - A * sa;      // wi
    coef[g * 4 + 2] = C * ca - D * sa;       // vr
    coef[g * 4 + 3] = -(C * sa + D * ca);    // vi
  }
}

// K1: one wave64 per sample; state fully register-resident (32 VGPRs)
__global__ __launch_bounds__(256) void circuit_kernel(const float* __restrict__ x,
                                                      const float* __restrict__ coef,
                                                      float* __restrict__ out) {
  const int lane = threadIdx.x & 63;
  const int wid = __builtin_amdgcn_readfirstlane(
      (int)((blockIdx.x * blockDim.x + threadIdx.x) >> 6));

  float sr[16], si[16];
  #pragma unroll
  for (int r = 0; r < 16; ++r) { sr[r] = 0.f; si[r] = 0.f; }
  sr[0] = (lane == 0) ? 1.f : 0.f;

  const float* xrow = x + wid * NQ;
  enc_gate<0>(xrow, sr, si, lane);
  enc_gate<1>(xrow, sr, si, lane);
  enc_gate<2>(xrow, sr, si, lane);
  enc_gate<3>(xrow, sr, si, lane);
  enc_gate<4>(xrow, sr, si, lane);
  enc_gate<5>(xrow, sr, si, lane);
  enc_gate<6>(xrow, sr, si, lane);
  enc_gate<7>(xrow, sr, si, lane);
  enc_gate<8>(xrow, sr, si, lane);
  enc_gate<9>(xrow, sr, si, lane);

  #pragma unroll 1
  for (int l = 0; l < 3; ++l) {
    rot_gate<0>(coef, l, sr, si, lane);
    rot_gate<1>(coef, l, sr, si, lane);
    rot_gate<2>(coef, l, sr, si, lane);
    rot_gate<3>(coef, l, sr, si, lane);
    rot_gate<4>(coef, l, sr, si, lane);
    rot_gate<5>(coef, l, sr, si, lane);
    rot_gate<6>(coef, l, sr, si, lane);
    rot_gate<7>(coef, l, sr, si, lane);
    rot_gate<8>(coef, l, sr, si, lane);
    rot_gate<9>(coef, l, sr, si, lane);
    // CNOT chain, control qubit i -> bit 9-i, target bit 8-i
    cnot_ll(sr, si, lane, 32, 16);  // bits (9,8)
    cnot_ll(sr, si, lane, 16, 8);   // (8,7)
    cnot_ll(sr, si, lane, 8, 4);    // (7,6)
    cnot_ll(sr, si, lane, 4, 2);    // (6,5)
    cnot_ll(sr, si, lane, 2, 1);    // (5,4)
    cnot_l0_r3(sr, si, lane);       // (4,3)
    cnot_rr<3, 2>(sr, si);          // (3,2) free
    cnot_rr<2, 1>(sr, si);          // (2,1) free
    cnot_rr<1, 0>(sr, si);          // (1,0) free
  }

  // <Z_q> epilogue
  float p[16];
  float tot = 0.f;
  #pragma unroll
  for (int r = 0; r < 16; ++r) {
    p[r] = sr[r] * sr[r] + si[r] * si[r];
    tot += p[r];
  }
  float e[10];
  #pragma unroll
  for (int q = 0; q < 6; ++q) {           // qubits 0..5 -> lane bits 5-q
    int lm = 1 << (5 - q);
    e[q] = (lane & lm) ? -tot : tot;
  }
  #pragma unroll
  for (int q = 6; q < 10; ++q) {          // qubits 6..9 -> reg bits 9-q
    const int m = 1 << (9 - q);
    float s = 0.f;
    #pragma unroll
    for (int r = 0; r < 16; ++r) s += (r & m) ? -p[r] : p[r];
    e[q] = s;
  }
  #pragma unroll
  for (int off = 32; off >= 1; off >>= 1) {
    #pragma unroll
    for (int q = 0; q < 10; ++q) e[q] += shflx(e[q], off);
  }
  if (lane == 0) {
    #pragma unroll
    for (int q = 0; q < 10; ++q) out[wid * NQ + q] = e[q];
  }
}

// K2: per-qubit batch mean / rstd
__global__ __launch_bounds__(256) void stats_kernel(const float* __restrict__ exps,
                                                    float* __restrict__ stats) {
  const int q = blockIdx.x;
  const int tid = threadIdx.x;
  float sum = 0.f, sumsq = 0.f;
  for (int i = tid; i < NSAMP; i += 256) {
    float v = exps[i * NQ + q];
    sum += v;
    sumsq += v * v;
  }
  __shared__ float l1[256], l2[256];
  l1[tid] = sum; l2[tid] = sumsq;
  __syncthreads();
  for (int s = 128; s > 0; s >>= 1) {
    if (tid < s) { l1[tid] += l1[tid + s]; l2[tid] += l2[tid + s]; }
    __syncthreads();
  }
  if (tid == 0) {
    float mean = l1[0] * (1.f / NSAMP);
    float var = l2[0] * (1.f / NSAMP) - mean * mean;
    if (var < 0.f) var = 0.f;
    stats[q] = mean;
    stats[NQ + q] = rsqrtf(var + BN_EPS);
  }
}

// K3: in-place BatchNorm
__global__ __launch_bounds__(256) void bn_kernel(float* __restrict__ out,
                                                 const float* __restrict__ stats,
                                                 const float* __restrict__ gamma,
                                                 const float* __restrict__ beta) {
  int i = blockIdx.x * 256 + threadIdx.x;
  if (i < NSAMP * NQ) {
    int q = i % NQ;
    float v = out[i];
    out[i] = gamma[q] * (v - stats[q]) * stats[NQ + q] + beta[q];
  }
}

extern "C" void kernel_launch(void* const* d_in, const int* in_sizes, int n_in,
                              void* d_out, int out_size, void* d_ws, size_t ws_size,
                              hipStream_t stream) {
  const float* x      = (const float*)d_in[0];
  const float* params = (const float*)d_in[1];
  const float* gamma  = (const float*)d_in[2];
  const float* beta   = (const float*)d_in[3];
  float* out = (float*)d_out;
  float* stats = (float*)d_ws;            // [0..9]=mean, [10..19]=rstd
  float* coef = (float*)d_ws + 32;        // 30 gates * 4 floats

  coef_kernel<<<1, 32, 0, stream>>>(params, coef);
  circuit_kernel<<<NSAMP / 4, 256, 0, stream>>>(x, coef, out);
  stats_kernel<<<NQ, 256, 0, stream>>>(out, stats);
  bn_kernel<<<(NSAMP * NQ + 255) / 256, 256, 0, stream>>>(out, stats, gamma, beta);
}

// Round 4
// 229.354 us; speedup vs baseline: 1.1948x; 1.1948x over previous
//
#include <hip/hip_runtime.h>

#define NQ 10
#define NSAMP 16384
#define BN_EPS 1e-5f

__device__ __forceinline__ float shflx(float v, int m) {
  return __shfl_xor(v, m, 64);
}

// -------- compile-time mask tables (deferred CNOT-chain permutation) --------
// Index bit b (9..0) = wire (9-b). Lane holds bits 9..4 (lane bit k = index
// bit k+4), regs hold bits 3..0. Stored array S is never permuted; after k
// CNOT chains the true state L satisfies S[p] = L[P_k p] with P_k = C^{-k},
// C = I + N (N = bit-downshift). Verified by explicit trace simulation:
//   e9 -> chains -> bits {9,8,5,4,1,0} = C^{-3} e9  (matches)
//   e4 -> chains -> bits {4,3,0}       = C^{-3} e4  (matches)
// Gate on logical bit b at layer l:
//   partner mask = column b of P_l^{-1} = C^l e_b   (l=1: {b,b-1}; l=2: {b,b-2})
//   hi-parity    = row b of P_l = C^{-l}            (l=1: {b..9}; l=2: {b,b+2,..})
constexpr int ML_[3][10] = {
  {0x20,0x10,0x08,0x04,0x02,0x01, 0,   0,   0,   0},
  {0x30,0x18,0x0C,0x06,0x03,0x01, 0,   0,   0,   0},
  {0x28,0x14,0x0A,0x05,0x02,0x01, 0,   0,   0,   0}};
constexpr int MR_[3][10] = {
  {0,0,0,0,0,0,   0x8,0x4,0x2,0x1},
  {0,0,0,0,0,0x8, 0xC,0x6,0x3,0x1},
  {0,0,0,0,0x8,0x4,0xA,0x5,0x2,0x1}};
constexpr int HL_[3][10] = {
  {0x20,0x10,0x08,0x04,0x02,0x01, 0,   0,   0,   0},
  {0x20,0x30,0x38,0x3C,0x3E,0x3F, 0x3F,0x3F,0x3F,0x3F},
  {0x20,0x10,0x28,0x14,0x2A,0x15, 0x2A,0x15,0x2A,0x15}};
constexpr int HR_[3][10] = {
  {0,0,0,0,0,0, 0x8,0x4,0x2,0x1},
  {0,0,0,0,0,0, 0x8,0xC,0xE,0xF},
  {0,0,0,0,0,0, 0x8,0x4,0xA,0x5}};
// Epilogue sign masks: row b of C^{-3} = I+N+N^4+N^5+N^8+N^9
//   -> bits {b, b+1, b+4, b+5, b+8, b+9} ∩ [0,9], b = 9-q.
// q=0:{9} q=1:{8,9} q=2:{7,8} q=3:{6,7} q=4:{5,6,9} q=5:{4,5,8,9}
// q=6:{3,4,7,8} q=7:{2,3,6,7} q=8:{1,2,5,6,9} q=9:{0,1,4,5,8,9}
// (R2/R3 bug: q=8 dropped bit b+8=9 -> EHL[8] must be 0x26, not 0x06.)
constexpr int EHL[10] = {0x20,0x30,0x18,0x0C,0x26,0x33,0x19,0x0C,0x26,0x33};
constexpr int EHR[10] = {0,   0,   0,   0,   0,   0,   0x8, 0xC, 0x6, 0x3};

constexpr int hibit4(int m) {
  return m >= 8 ? 8 : (m >= 4 ? 4 : (m >= 2 ? 2 : (m ? 1 : 0)));
}
constexpr bool par4(int v) { return ((v >> 3 & 1) ^ (v >> 2 & 1) ^ (v >> 1 & 1) ^ (v & 1)) != 0; }

// SU(2) gate [[w,-conj(v)],[v,conj(w)]] with partner mask (ML lane, MR reg)
// and hi-parity masks (HL lane, HR reg). sigma = hi ? +1 : -1:
//   sr' = wr*ar + sigma*wi*ai + sigma*vr*br - vi*bi
//   si' = wr*ai - sigma*wi*ar + sigma*vr*bi + vi*br
template<int ML, int MR, int HL, int HR>
__device__ __forceinline__ void gate(float* __restrict__ sr, float* __restrict__ si,
                                     int lane, float wr, float wi, float vr, float vi) {
  float swi, svr;  // coefficient values for reg-parity == 0
  if constexpr (HL != 0) {
    const bool lhi = (__builtin_popcount(lane & HL) & 1) != 0;
    swi = lhi ? wi : -wi;
    svr = lhi ? vr : -vr;
  } else {
    swi = -wi; svr = -vr;
  }
  if constexpr (MR == 0) {
    #pragma unroll
    for (int r = 0; r < 16; ++r) {
      float ar = sr[r], ai = si[r];
      float br = shflx(ar, ML), bi = shflx(ai, ML);
      const float awi = par4(r & HR) ? -swi : swi;
      const float avr = par4(r & HR) ? -svr : svr;
      sr[r] = wr * ar + awi * ai + avr * br - vi * bi;
      si[r] = wr * ai - awi * ar + avr * bi + vi * br;
    }
  } else {
    constexpr int HB = hibit4(MR);
    #pragma unroll
    for (int r = 0; r < 16; ++r) {
      if (!(r & HB)) {
        const int r2 = r ^ MR;
        float a0r = sr[r],  a0i = si[r];
        float a1r = sr[r2], a1i = si[r2];
        float b0r, b0i, b1r, b1i;
        if constexpr (ML != 0) {
          b0r = shflx(a1r, ML); b0i = shflx(a1i, ML);
          b1r = shflx(a0r, ML); b1i = shflx(a0i, ML);
        } else {
          b0r = a1r; b0i = a1i; b1r = a0r; b1i = a0i;
        }
        {
          const float awi = par4(r & HR) ? -swi : swi;
          const float avr = par4(r & HR) ? -svr : svr;
          sr[r] = wr * a0r + awi * a0i + avr * b0r - vi * b0i;
          si[r] = wr * a0i - awi * a0r + avr * b0i + vi * b0r;
        }
        {
          const float awi = par4(r2 & HR) ? -swi : swi;
          const float avr = par4(r2 & HR) ? -svr : svr;
          sr[r2] = wr * a1r + awi * a1i + avr * b1r - vi * b1i;
          si[r2] = wr * a1i - awi * a1r + avr * b1i + vi * b1r;
        }
      }
    }
  }
}

template<int L, int Q>
__device__ __forceinline__ void rotg(const float4* __restrict__ cg, float* sr, float* si, int lane) {
  const float4 g = cg[L * 10 + Q];
  gate<ML_[L][Q], MR_[L][Q], HL_[L][Q], HR_[L][Q]>(sr, si, lane, g.x, g.y, g.z, g.w);
}

template<int Q>
__device__ __forceinline__ float zexp(const float* __restrict__ p, int lane, float tot) {
  float s;
  if constexpr (EHR[Q] == 0) {
    s = tot;
  } else {
    s = 0.f;
    #pragma unroll
    for (int r = 0; r < 16; ++r) s = par4(r & EHR[Q]) ? s - p[r] : s + p[r];
  }
  const bool neg = (__builtin_popcount(lane & EHL[Q]) & 1) != 0;
  return neg ? -s : s;
}

// K0: 30 fused SU(2) matrices RY*RX*RZ from params (batch-uniform)
__global__ void coef_kernel(const float* __restrict__ params, float* __restrict__ coef) {
  int g = threadIdx.x;
  if (g < 30) {
    float t0 = params[g * 3 + 0] * 0.5f;
    float t1 = params[g * 3 + 1] * 0.5f;
    float t2 = params[g * 3 + 2] * 0.5f;
    float sa, ca, s2, c2, s3, c3;
    __sincosf(t0, &sa, &ca);
    __sincosf(t1, &s2, &c2);
    __sincosf(t2, &s3, &c3);
    float A = c3 * c2, Bv = s3 * s2, C = s3 * c2, D = c3 * s2;
    coef[g * 4 + 0] = A * ca + Bv * sa;      // wr
    coef[g * 4 + 1] = Bv * ca - A * sa;      // wi
    coef[g * 4 + 2] = C * ca - D * sa;       // vr
    coef[g * 4 + 3] = -(C * sa + D * ca);    // vi
  }
}

// K1: one wave64 per sample; 1024 amplitudes fully register-resident
__global__ __launch_bounds__(256) void circuit_kernel(const float* __restrict__ x,
                                                      const float* __restrict__ coef,
                                                      float* __restrict__ out) {
  const int lane = threadIdx.x & 63;
  const int wid = __builtin_amdgcn_readfirstlane(
      (int)((blockIdx.x * blockDim.x + threadIdx.x) >> 6));
  const float4* cg = (const float4*)coef;

  // ---- analytic RY-encoded product state (real) ----
  const float* xrow = x + wid * NQ;
  float c[10], s[10];
  #pragma unroll
  for (int q = 0; q < 10; ++q) __sincosf(xrow[q] * 0.5f, &s[q], &c[q]);

  float lf = ((lane >> 5) & 1 ? s[0] : c[0]);
  lf *= ((lane >> 4) & 1 ? s[1] : c[1]);
  lf *= ((lane >> 3) & 1 ? s[2] : c[2]);
  lf *= ((lane >> 2) & 1 ? s[3] : c[3]);
  lf *= ((lane >> 1) & 1 ? s[4] : c[4]);
  lf *= ((lane)      & 1 ? s[5] : c[5]);

  float f67[4], f89[4];
  #pragma unroll
  for (int i = 0; i < 4; ++i) {
    f67[i] = (i & 2 ? s[6] : c[6]) * (i & 1 ? s[7] : c[7]);
    f89[i] = (i & 2 ? s[8] : c[8]) * (i & 1 ? s[9] : c[9]);
  }
  float sr[16], si[16];
  #pragma unroll
  for (int r = 0; r < 16; ++r) {
    sr[r] = lf * f67[r >> 2] * f89[r & 3];
    si[r] = 0.f;
  }

  // ---- 3 layers of fused rotations; CNOT chains are free (index relabeling) ----
  rotg<0,0>(cg,sr,si,lane); rotg<0,1>(cg,sr,si,lane); rotg<0,2>(cg,sr,si,lane);
  rotg<0,3>(cg,sr,si,lane); rotg<0,4>(cg,sr,si,lane); rotg<0,5>(cg,sr,si,lane);
  rotg<0,6>(cg,sr,si,lane); rotg<0,7>(cg,sr,si,lane); rotg<0,8>(cg,sr,si,lane);
  rotg<0,9>(cg,sr,si,lane);

  rotg<1,0>(cg,sr,si,lane); rotg<1,1>(cg,sr,si,lane); rotg<1,2>(cg,sr,si,lane);
  rotg<1,3>(cg,sr,si,lane); rotg<1,4>(cg,sr,si,lane); rotg<1,5>(cg,sr,si,lane);
  rotg<1,6>(cg,sr,si,lane); rotg<1,7>(cg,sr,si,lane); rotg<1,8>(cg,sr,si,lane);
  rotg<1,9>(cg,sr,si,lane);

  rotg<2,0>(cg,sr,si,lane); rotg<2,1>(cg,sr,si,lane); rotg<2,2>(cg,sr,si,lane);
  rotg<2,3>(cg,sr,si,lane); rotg<2,4>(cg,sr,si,lane); rotg<2,5>(cg,sr,si,lane);
  rotg<2,6>(cg,sr,si,lane); rotg<2,7>(cg,sr,si,lane); rotg<2,8>(cg,sr,si,lane);
  rotg<2,9>(cg,sr,si,lane);

  // ---- <Z_q> epilogue with C^{-3} parity rows ----
  float p[16];
  float tot = 0.f;
  #pragma unroll
  for (int r = 0; r < 16; ++r) {
    p[r] = sr[r] * sr[r] + si[r] * si[r];
    tot += p[r];
  }
  float e[10];
  e[0] = zexp<0>(p, lane, tot); e[1] = zexp<1>(p, lane, tot);
  e[2] = zexp<2>(p, lane, tot); e[3] = zexp<3>(p, lane, tot);
  e[4] = zexp<4>(p, lane, tot); e[5] = zexp<5>(p, lane, tot);
  e[6] = zexp<6>(p, lane, tot); e[7] = zexp<7>(p, lane, tot);
  e[8] = zexp<8>(p, lane, tot); e[9] = zexp<9>(p, lane, tot);

  #pragma unroll
  for (int off = 32; off >= 1; off >>= 1) {
    #pragma unroll
    for (int q = 0; q < 10; ++q) e[q] += shflx(e[q], off);
  }
  if (lane == 0) {
    #pragma unroll
    for (int q = 0; q < 10; ++q) out[wid * NQ + q] = e[q];
  }
}

// K2: per-qubit batch mean / rstd
__global__ __launch_bounds__(256) void stats_kernel(const float* __restrict__ exps,
                                                    float* __restrict__ stats) {
  const int q = blockIdx.x;
  const int tid = threadIdx.x;
  float sum = 0.f, sumsq = 0.f;
  for (int i = tid; i < NSAMP; i += 256) {
    float v = exps[i * NQ + q];
    sum += v;
    sumsq += v * v;
  }
  __shared__ float l1[256], l2[256];
  l1[tid] = sum; l2[tid] = sumsq;
  __syncthreads();
  for (int s2 = 128; s2 > 0; s2 >>= 1) {
    if (tid < s2) { l1[tid] += l1[tid + s2]; l2[tid] += l2[tid + s2]; }
    __syncthreads();
  }
  if (tid == 0) {
    float mean = l1[0] * (1.f / NSAMP);
    float var = l2[0] * (1.f / NSAMP) - mean * mean;
    if (var < 0.f) var = 0.f;
    stats[q] = mean;
    stats[NQ + q] = rsqrtf(var + BN_EPS);
  }
}

// K3: in-place BatchNorm
__global__ __launch_bounds__(256) void bn_kernel(float* __restrict__ out,
                                                 const float* __restrict__ stats,
                                                 const float* __restrict__ gamma,
                                                 const float* __restrict__ beta) {
  int i = blockIdx.x * 256 + threadIdx.x;
  if (i < NSAMP * NQ) {
    int q = i % NQ;
    float v = out[i];
    out[i] = gamma[q] * (v - stats[q]) * stats[NQ + q] + beta[q];
  }
}

extern "C" void kernel_launch(void* const* d_in, const int* in_sizes, int n_in,
                              void* d_out, int out_size, void* d_ws, size_t ws_size,
                              hipStream_t stream) {
  const float* x      = (const float*)d_in[0];
  const float* params = (const float*)d_in[1];
  const float* gamma  = (const float*)d_in[2];
  const float* beta   = (const float*)d_in[3];
  float* out = (float*)d_out;
  float* stats = (float*)d_ws;            // [0..9]=mean, [10..19]=rstd
  float* coef = (float*)d_ws + 32;        // 30 gates * 4 floats (16B aligned)

  coef_kernel<<<1, 32, 0, stream>>>(params, coef);
  circuit_kernel<<<NSAMP / 4, 256, 0, stream>>>(x, coef, out);
  stats_kernel<<<NQ, 256, 0, stream>>>(out, stats);
  bn_kernel<<<(NSAMP * NQ + 255) / 256, 256, 0, stream>>>(out, stats, gamma, beta);
}

// Round 5
// 169.917 us; speedup vs baseline: 1.6127x; 1.3498x over previous
//
#include <hip/hip_runtime.h>

#define NQ 10
#define NSAMP 16384
#define BN_EPS 1e-5f

__device__ __forceinline__ float shflx(float v, int m) {
  return __shfl_xor(v, m, 64);
}

// -------- compile-time mask tables (deferred CNOT-chain permutation) --------
// Index bit b (9..0) = wire (9-b). Lane holds bits 9..4 (lane bit k = index
// bit k+4), regs hold bits 3..0. Stored array S is never permuted; after k
// CNOT chains the true state L satisfies S[p] = L[P_k p] with P_k = C^{-k},
// C = I + N (N = bit-downshift). Verified by explicit trace simulation:
//   e9 -> chains -> bits {9,8,5,4,1,0} = C^{-3} e9  (matches)
//   e4 -> chains -> bits {4,3,0}       = C^{-3} e4  (matches)
// Gate on logical bit b at layer l (l = chains already applied):
//   partner mask = C^l e_b   (l=1: {b,b-1}; l=2: {b,b-2})
//   hi-parity    = row b of C^{-l}  (l=1: {b..9}; l=2: {b,b+2,..})
// Layer 0 (l=0, identity) is FOLDED into the initial product state and has
// no table entries used.
constexpr int ML_[3][10] = {
  {0x20,0x10,0x08,0x04,0x02,0x01, 0,   0,   0,   0},
  {0x30,0x18,0x0C,0x06,0x03,0x01, 0,   0,   0,   0},
  {0x28,0x14,0x0A,0x05,0x02,0x01, 0,   0,   0,   0}};
constexpr int MR_[3][10] = {
  {0,0,0,0,0,0,   0x8,0x4,0x2,0x1},
  {0,0,0,0,0,0x8, 0xC,0x6,0x3,0x1},
  {0,0,0,0,0x8,0x4,0xA,0x5,0x2,0x1}};
constexpr int HL_[3][10] = {
  {0x20,0x10,0x08,0x04,0x02,0x01, 0,   0,   0,   0},
  {0x20,0x30,0x38,0x3C,0x3E,0x3F, 0x3F,0x3F,0x3F,0x3F},
  {0x20,0x10,0x28,0x14,0x2A,0x15, 0x2A,0x15,0x2A,0x15}};
constexpr int HR_[3][10] = {
  {0,0,0,0,0,0, 0x8,0x4,0x2,0x1},
  {0,0,0,0,0,0, 0x8,0xC,0xE,0xF},
  {0,0,0,0,0,0, 0x8,0x4,0xA,0x5}};
// Epilogue sign masks: row b of C^{-3} = I+N+N^4+N^5+N^8+N^9
//   -> bits {b, b+1, b+4, b+5, b+8, b+9} ∩ [0,9], b = 9-q.
// q=0:{9} q=1:{8,9} q=2:{7,8} q=3:{6,7} q=4:{5,6,9} q=5:{4,5,8,9}
// q=6:{3,4,7,8} q=7:{2,3,6,7} q=8:{1,2,5,6,9} q=9:{0,1,4,5,8,9}
constexpr int EHL[10] = {0x20,0x30,0x18,0x0C,0x26,0x33,0x19,0x0C,0x26,0x33};
constexpr int EHR[10] = {0,   0,   0,   0,   0,   0,   0x8, 0xC, 0x6, 0x3};

constexpr int hibit4(int m) {
  return m >= 8 ? 8 : (m >= 4 ? 4 : (m >= 2 ? 2 : (m ? 1 : 0)));
}
constexpr bool par4(int v) { return ((v >> 3 & 1) ^ (v >> 2 & 1) ^ (v >> 1 & 1) ^ (v & 1)) != 0; }

// SU(2) gate [[w,-conj(v)],[v,conj(w)]] with partner mask (ML lane, MR reg)
// and hi-parity masks (HL lane, HR reg). sigma = hi ? +1 : -1:
//   sr' = wr*ar + sigma*wi*ai + sigma*vr*br - vi*bi
//   si' = wr*ai - sigma*wi*ar + sigma*vr*bi + vi*br
template<int ML, int MR, int HL, int HR>
__device__ __forceinline__ void gate(float* __restrict__ sr, float* __restrict__ si,
                                     int lane, float wr, float wi, float vr, float vi) {
  float swi, svr;  // coefficient values for reg-parity == 0
  if constexpr (HL != 0) {
    const bool lhi = (__builtin_popcount(lane & HL) & 1) != 0;
    swi = lhi ? wi : -wi;
    svr = lhi ? vr : -vr;
  } else {
    swi = -wi; svr = -vr;
  }
  if constexpr (MR == 0) {
    #pragma unroll
    for (int r = 0; r < 16; ++r) {
      float ar = sr[r], ai = si[r];
      float br = shflx(ar, ML), bi = shflx(ai, ML);
      const float awi = par4(r & HR) ? -swi : swi;
      const float avr = par4(r & HR) ? -svr : svr;
      sr[r] = wr * ar + awi * ai + avr * br - vi * bi;
      si[r] = wr * ai - awi * ar + avr * bi + vi * br;
    }
  } else {
    constexpr int HB = hibit4(MR);
    #pragma unroll
    for (int r = 0; r < 16; ++r) {
      if (!(r & HB)) {
        const int r2 = r ^ MR;
        float a0r = sr[r],  a0i = si[r];
        float a1r = sr[r2], a1i = si[r2];
        float b0r, b0i, b1r, b1i;
        if constexpr (ML != 0) {
          b0r = shflx(a1r, ML); b0i = shflx(a1i, ML);
          b1r = shflx(a0r, ML); b1i = shflx(a0i, ML);
        } else {
          b0r = a1r; b0i = a1i; b1r = a0r; b1i = a0i;
        }
        {
          const float awi = par4(r & HR) ? -swi : swi;
          const float avr = par4(r & HR) ? -svr : svr;
          sr[r] = wr * a0r + awi * a0i + avr * b0r - vi * b0i;
          si[r] = wr * a0i - awi * a0r + avr * b0i + vi * b0r;
        }
        {
          const float awi = par4(r2 & HR) ? -swi : swi;
          const float avr = par4(r2 & HR) ? -svr : svr;
          sr[r2] = wr * a1r + awi * a1i + avr * b1r - vi * b1i;
          si[r2] = wr * a1i - awi * a1r + avr * b1i + vi * b1r;
        }
      }
    }
  }
}

template<int L, int Q>
__device__ __forceinline__ void rotg(const float4* __restrict__ cg, float* sr, float* si, int lane) {
  const float4 g = cg[L * 10 + Q];
  gate<ML_[L][Q], MR_[L][Q], HL_[L][Q], HR_[L][Q]>(sr, si, lane, g.x, g.y, g.z, g.w);
}

template<int Q>
__device__ __forceinline__ float zexp(const float* __restrict__ p, int lane, float tot) {
  float s;
  if constexpr (EHR[Q] == 0) {
    s = tot;
  } else {
    s = 0.f;
    #pragma unroll
    for (int r = 0; r < 16; ++r) s = par4(r & EHR[Q]) ? s - p[r] : s + p[r];
  }
  const bool neg = (__builtin_popcount(lane & EHL[Q]) & 1) != 0;
  return neg ? -s : s;
}

// K0: 30 fused SU(2) matrices RY*RX*RZ from params (batch-uniform)
__global__ void coef_kernel(const float* __restrict__ params, float* __restrict__ coef) {
  int g = threadIdx.x;
  if (g < 30) {
    float t0 = params[g * 3 + 0] * 0.5f;
    float t1 = params[g * 3 + 1] * 0.5f;
    float t2 = params[g * 3 + 2] * 0.5f;
    float sa, ca, s2, c2, s3, c3;
    __sincosf(t0, &sa, &ca);
    __sincosf(t1, &s2, &c2);
    __sincosf(t2, &s3, &c3);
    float A = c3 * c2, Bv = s3 * s2, C = s3 * c2, D = c3 * s2;
    coef[g * 4 + 0] = A * ca + Bv * sa;      // wr
    coef[g * 4 + 1] = Bv * ca - A * sa;      // wi
    coef[g * 4 + 2] = C * ca - D * sa;       // vr
    coef[g * 4 + 3] = -(C * sa + D * ca);    // vi
  }
}

// K1: one wave64 per sample; 1024 amplitudes fully register-resident.
// Layer-0 rotations are folded into the initial product state:
// per qubit, (alpha,beta) = U_{0,q} * (cos, sin); state = tensor product.
__global__ __launch_bounds__(256) void circuit_kernel(const float* __restrict__ x,
                                                      const float* __restrict__ coef,
                                                      float* __restrict__ out) {
  const int lane = threadIdx.x & 63;
  const int wid = __builtin_amdgcn_readfirstlane(
      (int)((blockIdx.x * blockDim.x + threadIdx.x) >> 6));
  const float4* cg = (const float4*)coef;

  // ---- encoding + layer-0: per-qubit complex 2-vectors ----
  // alpha = w*c - conj(v)*s ; beta = v*c + conj(w)*s  (c,s real)
  const float* xrow = x + wid * NQ;
  float Ar[10], Ai[10], Br[10], Bi[10];
  #pragma unroll
  for (int q = 0; q < 10; ++q) {
    float sq, cq;
    __sincosf(xrow[q] * 0.5f, &sq, &cq);
    const float4 g = cg[q];  // layer-0 fused SU(2)
    Ar[q] = g.x * cq - g.z * sq;
    Ai[q] = g.y * cq + g.w * sq;
    Br[q] = g.z * cq + g.x * sq;
    Bi[q] = g.w * cq - g.y * sq;
  }

  // lane factor: product over qubits 0..5 (lane bits 5..0)
  float lr = (lane & 32) ? Br[0] : Ar[0];
  float li = (lane & 32) ? Bi[0] : Ai[0];
  #pragma unroll
  for (int q = 1; q < 6; ++q) {
    const int bit = 1 << (5 - q);
    const float tr = (lane & bit) ? Br[q] : Ar[q];
    const float ti = (lane & bit) ? Bi[q] : Ai[q];
    const float nr = lr * tr - li * ti;
    const float ni = lr * ti + li * tr;
    lr = nr; li = ni;
  }

  // register factors: qubits 6,7 (reg bits 3,2) and 8,9 (reg bits 1,0)
  float F67r[4], F67i[4], F89r[4], F89i[4];
  #pragma unroll
  for (int i = 0; i < 4; ++i) {
    const float a6r = (i & 2) ? Br[6] : Ar[6], a6i = (i & 2) ? Bi[6] : Ai[6];
    const float a7r = (i & 1) ? Br[7] : Ar[7], a7i = (i & 1) ? Bi[7] : Ai[7];
    F67r[i] = a6r * a7r - a6i * a7i;
    F67i[i] = a6r * a7i + a6i * a7r;
    const float a8r = (i & 2) ? Br[8] : Ar[8], a8i = (i & 2) ? Bi[8] : Ai[8];
    const float a9r = (i & 1) ? Br[9] : Ar[9], a9i = (i & 1) ? Bi[9] : Ai[9];
    F89r[i] = a8r * a9r - a8i * a9i;
    F89i[i] = a8r * a9i + a8i * a9r;
  }

  float sr[16], si[16];
  #pragma unroll
  for (int r = 0; r < 16; ++r) {
    const float tr = F67r[r >> 2] * F89r[r & 3] - F67i[r >> 2] * F89i[r & 3];
    const float ti = F67r[r >> 2] * F89i[r & 3] + F67i[r >> 2] * F89r[r & 3];
    sr[r] = lr * tr - li * ti;
    si[r] = lr * ti + li * tr;
  }

  // ---- layers 1,2 fused rotations; CNOT chains free (index relabeling) ----
  rotg<1,0>(cg,sr,si,lane); rotg<1,1>(cg,sr,si,lane); rotg<1,2>(cg,sr,si,lane);
  rotg<1,3>(cg,sr,si,lane); rotg<1,4>(cg,sr,si,lane); rotg<1,5>(cg,sr,si,lane);
  rotg<1,6>(cg,sr,si,lane); rotg<1,7>(cg,sr,si,lane); rotg<1,8>(cg,sr,si,lane);
  rotg<1,9>(cg,sr,si,lane);

  rotg<2,0>(cg,sr,si,lane); rotg<2,1>(cg,sr,si,lane); rotg<2,2>(cg,sr,si,lane);
  rotg<2,3>(cg,sr,si,lane); rotg<2,4>(cg,sr,si,lane); rotg<2,5>(cg,sr,si,lane);
  rotg<2,6>(cg,sr,si,lane); rotg<2,7>(cg,sr,si,lane); rotg<2,8>(cg,sr,si,lane);
  rotg<2,9>(cg,sr,si,lane);

  // ---- <Z_q> epilogue with C^{-3} parity rows ----
  float p[16];
  float tot = 0.f;
  #pragma unroll
  for (int r = 0; r < 16; ++r) {
    p[r] = sr[r] * sr[r] + si[r] * si[r];
    tot += p[r];
  }
  float e[10];
  e[0] = zexp<0>(p, lane, tot); e[1] = zexp<1>(p, lane, tot);
  e[2] = zexp<2>(p, lane, tot); e[3] = zexp<3>(p, lane, tot);
  e[4] = zexp<4>(p, lane, tot); e[5] = zexp<5>(p, lane, tot);
  e[6] = zexp<6>(p, lane, tot); e[7] = zexp<7>(p, lane, tot);
  e[8] = zexp<8>(p, lane, tot); e[9] = zexp<9>(p, lane, tot);

  #pragma unroll
  for (int off = 32; off >= 1; off >>= 1) {
    #pragma unroll
    for (int q = 0; q < 10; ++q) e[q] += shflx(e[q], off);
  }
  if (lane == 0) {
    #pragma unroll
    for (int q = 0; q < 10; ++q) out[wid * NQ + q] = e[q];
  }
}

// K2: per-qubit batch mean / rstd
__global__ __launch_bounds__(256) void stats_kernel(const float* __restrict__ exps,
                                                    float* __restrict__ stats) {
  const int q = blockIdx.x;
  const int tid = threadIdx.x;
  float sum = 0.f, sumsq = 0.f;
  for (int i = tid; i < NSAMP; i += 256) {
    float v = exps[i * NQ + q];
    sum += v;
    sumsq += v * v;
  }
  __shared__ float l1[256], l2[256];
  l1[tid] = sum; l2[tid] = sumsq;
  __syncthreads();
  for (int s2 = 128; s2 > 0; s2 >>= 1) {
    if (tid < s2) { l1[tid] += l1[tid + s2]; l2[tid] += l2[tid + s2]; }
    __syncthreads();
  }
  if (tid == 0) {
    float mean = l1[0] * (1.f / NSAMP);
    float var = l2[0] * (1.f / NSAMP) - mean * mean;
    if (var < 0.f) var = 0.f;
    stats[q] = mean;
    stats[NQ + q] = rsqrtf(var + BN_EPS);
  }
}

// K3: in-place BatchNorm
__global__ __launch_bounds__(256) void bn_kernel(float* __restrict__ out,
                                                 const float* __restrict__ stats,
                                                 const float* __restrict__ gamma,
                                                 const float* __restrict__ beta) {
  int i = blockIdx.x * 256 + threadIdx.x;
  if (i < NSAMP * NQ) {
    int q = i % NQ;
    float v = out[i];
    out[i] = gamma[q] * (v - stats[q]) * stats[NQ + q] + beta[q];
  }
}

extern "C" void kernel_launch(void* const* d_in, const int* in_sizes, int n_in,
                              void* d_out, int out_size, void* d_ws, size_t ws_size,
                              hipStream_t stream) {
  const float* x      = (const float*)d_in[0];
  const float* params = (const float*)d_in[1];
  const float* gamma  = (const float*)d_in[2];
  const float* beta   = (const float*)d_in[3];
  float* out = (float*)d_out;
  float* stats = (float*)d_ws;            // [0..9]=mean, [10..19]=rstd
  float* coef = (float*)d_ws + 32;        // 30 gates * 4 floats (16B aligned)

  coef_kernel<<<1, 32, 0, stream>>>(params, coef);
  circuit_kernel<<<NSAMP / 4, 256, 0, stream>>>(x, coef, out);
  stats_kernel<<<NQ, 256, 0, stream>>>(out, stats);
  bn_kernel<<<(NSAMP * NQ + 255) / 256, 256, 0, stream>>>(out, stats, gamma, beta);
}

// Round 6
// 160.592 us; speedup vs baseline: 1.7064x; 1.0581x over previous
//
#include <hip/hip_runtime.h>

#define NQ 10
#define NSAMP 16384
#define BN_EPS 1e-5f

// -------- cross-lane xor shuffle --------
// masks < 0x20: single ds_swizzle_b32 with immediate bit-mode pattern
//   (xor within 32-lane group == global xor for mask<32). No VALU, no addr reg.
// masks >= 0x20: ds_bpermute with a precomputed byte address (3 distinct).
template<int M>
__device__ __forceinline__ float shufx(float v, int a30, int a28, int a20) {
  if constexpr (M < 32) {
    return __int_as_float(__builtin_amdgcn_ds_swizzle(
        __float_as_int(v), (M << 10) | 0x1F));
  } else {
    const int addr = (M == 0x30) ? a30 : (M == 0x28) ? a28 : a20;
    return __int_as_float(__builtin_amdgcn_ds_bpermute(addr, __float_as_int(v)));
  }
}

// -------- compile-time mask tables (deferred CNOT-chain permutation) --------
// Index bit b (9..0) = wire (9-b). Lane holds bits 9..4, regs bits 3..0.
// Stored array S never permuted; after k chains L[P_k p] = S[p], P_k = C^{-k},
// C = I + N (bit-downshift). Verified by explicit trace simulation (R4).
// Gate on logical bit b at layer l: partner mask = C^l e_b; hi-parity = row b
// of C^{-l}. Layer 0 folded into the initial product state.
constexpr int ML_[3][10] = {
  {0x20,0x10,0x08,0x04,0x02,0x01, 0,   0,   0,   0},
  {0x30,0x18,0x0C,0x06,0x03,0x01, 0,   0,   0,   0},
  {0x28,0x14,0x0A,0x05,0x02,0x01, 0,   0,   0,   0}};
constexpr int MR_[3][10] = {
  {0,0,0,0,0,0,   0x8,0x4,0x2,0x1},
  {0,0,0,0,0,0x8, 0xC,0x6,0x3,0x1},
  {0,0,0,0,0x8,0x4,0xA,0x5,0x2,0x1}};
constexpr int HL_[3][10] = {
  {0x20,0x10,0x08,0x04,0x02,0x01, 0,   0,   0,   0},
  {0x20,0x30,0x38,0x3C,0x3E,0x3F, 0x3F,0x3F,0x3F,0x3F},
  {0x20,0x10,0x28,0x14,0x2A,0x15, 0x2A,0x15,0x2A,0x15}};
constexpr int HR_[3][10] = {
  {0,0,0,0,0,0, 0x8,0x4,0x2,0x1},
  {0,0,0,0,0,0, 0x8,0xC,0xE,0xF},
  {0,0,0,0,0,0, 0x8,0x4,0xA,0x5}};
// Epilogue sign masks: row b of C^{-3} = I+N+N^4+N^5+N^8+N^9, b = 9-q
// (bits {b,b+1,b+4,b+5,b+8,b+9} ∩ [0,9]); trace-verified in R4.
constexpr int EHL[10] = {0x20,0x30,0x18,0x0C,0x26,0x33,0x19,0x0C,0x26,0x33};
constexpr int EHR[10] = {0,   0,   0,   0,   0,   0,   0x8, 0xC, 0x6, 0x3};

constexpr int hibit4(int m) {
  return m >= 8 ? 8 : (m >= 4 ? 4 : (m >= 2 ? 2 : (m ? 1 : 0)));
}
constexpr bool par4(int v) { return ((v >> 3 & 1) ^ (v >> 2 & 1) ^ (v >> 1 & 1) ^ (v & 1)) != 0; }

// SU(2) gate [[w,-conj(v)],[v,conj(w)]], partner mask (ML lane, MR reg),
// hi-parity (HL lane, HR reg). sigma = hi ? +1 : -1:
//   sr' = wr*ar + sigma*wi*ai + sigma*vr*br - vi*bi
//   si' = wr*ai - sigma*wi*ar + sigma*vr*bi + vi*br
template<int ML, int MR, int HL, int HR>
__device__ __forceinline__ void gate(float* __restrict__ sr, float* __restrict__ si,
                                     int lane, int a30, int a28, int a20,
                                     float wr, float wi, float vr, float vi) {
  float swi, svr;  // coefficient values for reg-parity == 0
  if constexpr (HL != 0) {
    const bool lhi = (__builtin_popcount(lane & HL) & 1) != 0;
    swi = lhi ? wi : -wi;
    svr = lhi ? vr : -vr;
  } else {
    swi = -wi; svr = -vr;
  }
  if constexpr (MR == 0) {
    #pragma unroll
    for (int r = 0; r < 16; ++r) {
      float ar = sr[r], ai = si[r];
      float br = shufx<ML>(ar, a30, a28, a20);
      float bi = shufx<ML>(ai, a30, a28, a20);
      const float awi = par4(r & HR) ? -swi : swi;
      const float avr = par4(r & HR) ? -svr : svr;
      sr[r] = wr * ar + awi * ai + avr * br - vi * bi;
      si[r] = wr * ai - awi * ar + avr * bi + vi * br;
    }
  } else {
    constexpr int HB = hibit4(MR);
    #pragma unroll
    for (int r = 0; r < 16; ++r) {
      if (!(r & HB)) {
        const int r2 = r ^ MR;
        float a0r = sr[r],  a0i = si[r];
        float a1r = sr[r2], a1i = si[r2];
        float b0r, b0i, b1r, b1i;
        if constexpr (ML != 0) {
          b0r = shufx<ML>(a1r, a30, a28, a20);
          b0i = shufx<ML>(a1i, a30, a28, a20);
          b1r = shufx<ML>(a0r, a30, a28, a20);
          b1i = shufx<ML>(a0i, a30, a28, a20);
        } else {
          b0r = a1r; b0i = a1i; b1r = a0r; b1i = a0i;
        }
        {
          const float awi = par4(r & HR) ? -swi : swi;
          const float avr = par4(r & HR) ? -svr : svr;
          sr[r] = wr * a0r + awi * a0i + avr * b0r - vi * b0i;
          si[r] = wr * a0i - awi * a0r + avr * b0i + vi * b0r;
        }
        {
          const float awi = par4(r2 & HR) ? -swi : swi;
          const float avr = par4(r2 & HR) ? -svr : svr;
          sr[r2] = wr * a1r + awi * a1i + avr * b1r - vi * b1i;
          si[r2] = wr * a1i - awi * a1r + avr * b1i + vi * b1r;
        }
      }
    }
  }
}

template<int L, int Q>
__device__ __forceinline__ void rotg(const float4* __restrict__ cg,
                                     float* sr, float* si,
                                     int lane, int a30, int a28, int a20) {
  const float4 g = cg[L * 10 + Q];
  gate<ML_[L][Q], MR_[L][Q], HL_[L][Q], HR_[L][Q]>(
      sr, si, lane, a30, a28, a20, g.x, g.y, g.z, g.w);
}

template<int Q>
__device__ __forceinline__ float zexp(const float* __restrict__ p, int lane, float tot) {
  float s;
  if constexpr (EHR[Q] == 0) {
    s = tot;
  } else {
    s = 0.f;
    #pragma unroll
    for (int r = 0; r < 16; ++r) s = par4(r & EHR[Q]) ? s - p[r] : s + p[r];
  }
  const bool neg = (__builtin_popcount(lane & EHL[Q]) & 1) != 0;
  return neg ? -s : s;
}

// per-qubit encoded+layer0 2-vector: (alpha,beta) = U0q * (cos, sin)
__device__ __forceinline__ void enc2(const float4 g, float xq,
                                     float& ar, float& ai, float& br, float& bi) {
  float sq, cq;
  __sincosf(xq * 0.5f, &sq, &cq);
  ar = g.x * cq - g.z * sq;
  ai = g.y * cq + g.w * sq;
  br = g.z * cq + g.x * sq;
  bi = g.w * cq - g.y * sq;
}

__device__ __forceinline__ void cmul(float& zr, float& zi,
                                     float xr, float xi, float yr, float yi) {
  zr = xr * yr - xi * yi;
  zi = xr * yi + xi * yr;
}

// K0: 30 fused SU(2) matrices RY*RX*RZ from params (batch-uniform)
__global__ void coef_kernel(const float* __restrict__ params, float* __restrict__ coef) {
  int g = threadIdx.x;
  if (g < 30) {
    float t0 = params[g * 3 + 0] * 0.5f;
    float t1 = params[g * 3 + 1] * 0.5f;
    float t2 = params[g * 3 + 2] * 0.5f;
    float sa, ca, s2, c2, s3, c3;
    __sincosf(t0, &sa, &ca);
    __sincosf(t1, &s2, &c2);
    __sincosf(t2, &s3, &c3);
    float A = c3 * c2, Bv = s3 * s2, C = s3 * c2, D = c3 * s2;
    coef[g * 4 + 0] = A * ca + Bv * sa;      // wr
    coef[g * 4 + 1] = Bv * ca - A * sa;      // wi
    coef[g * 4 + 2] = C * ca - D * sa;       // vr
    coef[g * 4 + 3] = -(C * sa + D * ca);    // vi
  }
}

// K1: one wave64 per sample; 1024 amplitudes register-resident.
__global__ __launch_bounds__(256) void circuit_kernel(const float* __restrict__ x,
                                                      const float* __restrict__ coef,
                                                      float* __restrict__ out) {
  const int lane = threadIdx.x & 63;
  const int wid = __builtin_amdgcn_readfirstlane(
      (int)((blockIdx.x * blockDim.x + threadIdx.x) >> 6));
  const float4* cg = (const float4*)coef;

  const int a30 = (lane ^ 0x30) << 2;
  const int a28 = (lane ^ 0x28) << 2;
  const int a20 = (lane ^ 0x20) << 2;

  // ---- encoding + layer-0 folded: progressive tensor-product build ----
  const float* xrow = x + wid * NQ;
  float lr, li;
  {
    float ar, ai, br, bi;
    enc2(cg[0], xrow[0], ar, ai, br, bi);
    lr = (lane & 32) ? br : ar;
    li = (lane & 32) ? bi : ai;
  }
  #pragma unroll
  for (int q = 1; q < 6; ++q) {
    float ar, ai, br, bi;
    enc2(cg[q], xrow[q], ar, ai, br, bi);
    const int bit = 1 << (5 - q);
    const float tr = (lane & bit) ? br : ar;
    const float ti = (lane & bit) ? bi : ai;
    const float nr = lr * tr - li * ti;
    const float ni = lr * ti + li * tr;
    lr = nr; li = ni;
  }
  // reg qubits 6..9 -> reg bits 3..0, expanding 1->2->4->8->16 amps
  float sr[16], si[16];
  {
    float ar, ai, br, bi;
    float t2r[2], t2i[2], t4r[4], t4i[4], t8r[8], t8i[8];
    enc2(cg[6], xrow[6], ar, ai, br, bi);
    cmul(t2r[0], t2i[0], lr, li, ar, ai);
    cmul(t2r[1], t2i[1], lr, li, br, bi);
    enc2(cg[7], xrow[7], ar, ai, br, bi);
    #pragma unroll
    for (int j = 0; j < 2; ++j) {
      cmul(t4r[2*j+0], t4i[2*j+0], t2r[j], t2i[j], ar, ai);
      cmul(t4r[2*j+1], t4i[2*j+1], t2r[j], t2i[j], br, bi);
    }
    enc2(cg[8], xrow[8], ar, ai, br, bi);
    #pragma unroll
    for (int j = 0; j < 4; ++j) {
      cmul(t8r[2*j+0], t8i[2*j+0], t4r[j], t4i[j], ar, ai);
      cmul(t8r[2*j+1], t8i[2*j+1], t4r[j], t4i[j], br, bi);
    }
    enc2(cg[9], xrow[9], ar, ai, br, bi);
    #pragma unroll
    for (int j = 0; j < 8; ++j) {
      cmul(sr[2*j+0], si[2*j+0], t8r[j], t8i[j], ar, ai);
      cmul(sr[2*j+1], si[2*j+1], t8r[j], t8i[j], br, bi);
    }
  }

  // ---- layers 1,2 fused rotations; CNOT chains free (index relabeling) ----
  rotg<1,0>(cg,sr,si,lane,a30,a28,a20); rotg<1,1>(cg,sr,si,lane,a30,a28,a20);
  rotg<1,2>(cg,sr,si,lane,a30,a28,a20); rotg<1,3>(cg,sr,si,lane,a30,a28,a20);
  rotg<1,4>(cg,sr,si,lane,a30,a28,a20); rotg<1,5>(cg,sr,si,lane,a30,a28,a20);
  rotg<1,6>(cg,sr,si,lane,a30,a28,a20); rotg<1,7>(cg,sr,si,lane,a30,a28,a20);
  rotg<1,8>(cg,sr,si,lane,a30,a28,a20); rotg<1,9>(cg,sr,si,lane,a30,a28,a20);

  rotg<2,0>(cg,sr,si,lane,a30,a28,a20); rotg<2,1>(cg,sr,si,lane,a30,a28,a20);
  rotg<2,2>(cg,sr,si,lane,a30,a28,a20); rotg<2,3>(cg,sr,si,lane,a30,a28,a20);
  rotg<2,4>(cg,sr,si,lane,a30,a28,a20); rotg<2,5>(cg,sr,si,lane,a30,a28,a20);
  rotg<2,6>(cg,sr,si,lane,a30,a28,a20); rotg<2,7>(cg,sr,si,lane,a30,a28,a20);
  rotg<2,8>(cg,sr,si,lane,a30,a28,a20); rotg<2,9>(cg,sr,si,lane,a30,a28,a20);

  // ---- <Z_q> epilogue with C^{-3} parity rows ----
  float p[16];
  float tot = 0.f;
  #pragma unroll
  for (int r = 0; r < 16; ++r) {
    p[r] = sr[r] * sr[r] + si[r] * si[r];
    tot += p[r];
  }
  float e[10];
  e[0] = zexp<0>(p, lane, tot); e[1] = zexp<1>(p, lane, tot);
  e[2] = zexp<2>(p, lane, tot); e[3] = zexp<3>(p, lane, tot);
  e[4] = zexp<4>(p, lane, tot); e[5] = zexp<5>(p, lane, tot);
  e[6] = zexp<6>(p, lane, tot); e[7] = zexp<7>(p, lane, tot);
  e[8] = zexp<8>(p, lane, tot); e[9] = zexp<9>(p, lane, tot);

  #pragma unroll
  for (int q = 0; q < 10; ++q) {
    e[q] += shufx<0x20>(e[q], a30, a28, a20);
    e[q] += shufx<0x10>(e[q], a30, a28, a20);
    e[q] += shufx<0x08>(e[q], a30, a28, a20);
    e[q] += shufx<0x04>(e[q], a30, a28, a20);
    e[q] += shufx<0x02>(e[q], a30, a28, a20);
    e[q] += shufx<0x01>(e[q], a30, a28, a20);
  }
  if (lane == 0) {
    #pragma unroll
    for (int q = 0; q < 10; ++q) out[wid * NQ + q] = e[q];
  }
}

// K2: per-qubit batch mean / rstd
__global__ __launch_bounds__(256) void stats_kernel(const float* __restrict__ exps,
                                                    float* __restrict__ stats) {
  const int q = blockIdx.x;
  const int tid = threadIdx.x;
  float sum = 0.f, sumsq = 0.f;
  for (int i = tid; i < NSAMP; i += 256) {
    float v = exps[i * NQ + q];
    sum += v;
    sumsq += v * v;
  }
  __shared__ float l1[256], l2[256];
  l1[tid] = sum; l2[tid] = sumsq;
  __syncthreads();
  for (int s2 = 128; s2 > 0; s2 >>= 1) {
    if (tid < s2) { l1[tid] += l1[tid + s2]; l2[tid] += l2[tid + s2]; }
    __syncthreads();
  }
  if (tid == 0) {
    float mean = l1[0] * (1.f / NSAMP);
    float var = l2[0] * (1.f / NSAMP) - mean * mean;
    if (var < 0.f) var = 0.f;
    stats[q] = mean;
    stats[NQ + q] = rsqrtf(var + BN_EPS);
  }
}

// K3: in-place BatchNorm
__global__ __launch_bounds__(256) void bn_kernel(float* __restrict__ out,
                                                 const float* __restrict__ stats,
                                                 const float* __restrict__ gamma,
                                                 const float* __restrict__ beta) {
  int i = blockIdx.x * 256 + threadIdx.x;
  if (i < NSAMP * NQ) {
    int q = i % NQ;
    float v = out[i];
    out[i] = gamma[q] * (v - stats[q]) * stats[NQ + q] + beta[q];
  }
}

extern "C" void kernel_launch(void* const* d_in, const int* in_sizes, int n_in,
                              void* d_out, int out_size, void* d_ws, size_t ws_size,
                              hipStream_t stream) {
  const float* x      = (const float*)d_in[0];
  const float* params = (const float*)d_in[1];
  const float* gamma  = (const float*)d_in[2];
  const float* beta   = (const float*)d_in[3];
  float* out = (float*)d_out;
  float* stats = (float*)d_ws;            // [0..9]=mean, [10..19]=rstd
  float* coef = (float*)d_ws + 32;        // 30 gates * 4 floats (16B aligned)

  coef_kernel<<<1, 32, 0, stream>>>(params, coef);
  circuit_kernel<<<NSAMP / 4, 256, 0, stream>>>(x, coef, out);
  stats_kernel<<<NQ, 256, 0, stream>>>(out, stats);
  bn_kernel<<<(NSAMP * NQ + 255) / 256, 256, 0, stream>>>(out, stats, gamma, beta);
}